// Round 2
// baseline (15561.172 us; speedup 1.0000x reference)
//
#include <hip/hip_runtime.h>
#include <stdint.h>

// R6: 2-way N-split across WG pairs (from R5's 7774 us).
//  - 128 WGs: pair (bid, bid^64) shares batch rows [pid*16,+16); WG computes
//    all 4 gates for h-units [half*128,+128). Weights: 72 frags (288 VGPR)
//    ALL in registers -- WLs LDS array deleted, LDS weight reads gone.
//  - h exchange via d_ws ping-pong buffers (parity t&1) + monotonic flags
//    (agent-scope release/acquire). Flags zeroed by hipMemsetAsync pre-launch.
//  - Partner h_{t} loaded straight into MFMA A-frags (phf[4]) after per-wave
//    acquire poll at step end; consumed next step (y + partner K-chunks).
//  - y computed redundantly by wave0 of BOTH halves (needed for feedback);
//    only half 0 writes out. Barriers/step: 2 warm, 3 auto (same as R5).
//  - Weight arrays indexed compile-time only (bwx/bwo/bwp) -- no scratch.

#define B_TOTAL   1024
#define H_DIM     256
#define F_WARM    32
#define F_AUTO    24
#define O_DIM     8
#define T_WARM    512
#define T_TOTAL   1024
#define N4H       1024
#define A_STR     168   // x(32)+h(128)+pad(8): 336 B/row, 16B-aligned, 2-way banks

typedef __attribute__((ext_vector_type(8))) short short8;
typedef __attribute__((ext_vector_type(4))) float float4v;

#define GLOBAL_AS __attribute__((address_space(1)))
#define LDS_AS    __attribute__((address_space(3)))

__device__ __forceinline__ short f2bf(float x) {
    union { float f; uint32_t u; } v; v.f = x;
    uint32_t r = v.u + 0x7FFFu + ((v.u >> 16) & 1u);   // RNE
    return (short)(r >> 16);
}
__device__ __forceinline__ float sigmoid_(float x) {
    const float e = __expf(-x);
    return __builtin_amdgcn_rcpf(1.0f + e);
}
__device__ __forceinline__ float tanh_(float x) {
    const float e = __expf(-2.0f * fabsf(x));
    const float t = (1.0f - e) * __builtin_amdgcn_rcpf(1.0f + e);
    return x >= 0.0f ? t : -t;
}

__global__ __launch_bounds__(256, 1)
void lstm_pair(const float* __restrict__ c0, const float* __restrict__ h0,
               const float* __restrict__ warm, const float* __restrict__ autoin,
               const float* __restrict__ W_ih, const float* __restrict__ W_hh,
               const float* __restrict__ bvec, const float* __restrict__ W_out,
               const float* __restrict__ b_out, float* __restrict__ out,
               unsigned short* __restrict__ ws)
{
    const int tid  = threadIdx.x;
    const int w    = tid >> 6;        // wave 0..3 -> own h-units [w*32, +32)
    const int l    = tid & 63;
    const int n16  = l & 15;          // MFMA n / A row (m)
    const int kg   = l >> 4;          // k-group 0..3
    const int bid  = blockIdx.x;
    const int half = bid >> 6;        // N-half: h-units [half*128, +128)
    const int row0 = (bid & 63) * 16; // batch rows
    const int hb   = half * 128;      // own h base (global h index)
    const int qb   = 128 - hb;        // partner h base

    uint32_t*       myflag = (uint32_t*)((char*)ws + (size_t)bid * 64);
    const uint32_t* pflag  = (const uint32_t*)((char*)ws + (size_t)(bid ^ 64) * 64);
    unsigned short* exch   = (unsigned short*)((char*)ws + 8192);
    unsigned short*       obuf0 = exch + (size_t)bid * 2 * 2048;
    const unsigned short* pbuf0 = exch + (size_t)(bid ^ 64) * 2 * 2048;

    // LDS: 5376 (A) + 8192 (W_out frags) + 2048 (bias) + 2048 (xstage) ~ 17.7 KB
    __shared__ __align__(16) short Alds[16 * A_STR];    // [x(32) | own h(128) | pad]
    __shared__ __align__(16) unsigned short wsWl[4096]; // W_out MFMA B-frags
    __shared__ float biasL[512];                        // own 4 gates x 128
    __shared__ __align__(16) float xstage[512];         // x_{t+1} prefetch

    // ---- W_out frags -> LDS (kk=0..7 over K=256, cols 0..15, n>=8 zero) ----
    for (int idx = tid; idx < 4096; idx += 256) {
        const int i = idx & 7, lane = (idx >> 3) & 63, kk = idx >> 9;
        const int k = kk * 32 + (lane >> 4) * 8 + i;
        const int n = lane & 15;
        wsWl[idx] = (unsigned short)((n < O_DIM) ? f2bf(W_out[k * O_DIM + n]) : (short)0);
    }
    // ---- bias: own 512 cols, layout [g][128] ----
    #pragma unroll
    for (int e = 0; e < 2; ++e) {
        const int idx = tid + e * 256;
        const int g = idx >> 7, loc = idx & 127;
        biasL[idx] = bvec[g * 256 + hb + loc];
    }

    // ---- register weights: 72 frags = 288 VGPR (compile-time indexed) ----
    short8 bwx[4][2];       // x chunk (W_ih rows 0..31)
    short8 bwo[4][4][2];    // own-h chunks c=0..3 (W_hh rows hb+c*32..)
    short8 bwp[4][4][2];    // partner-h chunks   (W_hh rows qb+c*32..)
    #pragma unroll
    for (int g = 0; g < 4; ++g)
        #pragma unroll
        for (int j = 0; j < 2; ++j) {
            const int col = g * 256 + hb + w * 32 + j * 16 + n16;
            {
                short8 f;
                #pragma unroll
                for (int i = 0; i < 8; ++i)
                    f[i] = f2bf(W_ih[(kg * 8 + i) * N4H + col]);
                bwx[g][j] = f;
            }
            #pragma unroll
            for (int c = 0; c < 4; ++c) {
                short8 f, p;
                #pragma unroll
                for (int i = 0; i < 8; ++i) {
                    const int kr = c * 32 + kg * 8 + i;
                    f[i] = f2bf(W_hh[(hb + kr) * N4H + col]);
                    p[i] = f2bf(W_hh[(qb + kr) * N4H + col]);
                }
                bwo[c][g][j] = f;
                bwp[c][g][j] = p;
            }
        }

    const float bout = (w == 0 && n16 < O_DIM) ? b_out[n16] : 0.0f;

    // ---- c state: own cols only; creg[j][r], row = kg*4+r ----
    float creg[2][4];
    #pragma unroll
    for (int j = 0; j < 2; ++j)
        #pragma unroll
        for (int r = 0; r < 4; ++r)
            creg[j][r] = c0[(size_t)(row0 + kg * 4 + r) * H_DIM
                            + (hb + w * 32 + j * 16 + n16)];

    // ---- initial A: x_0 + own h0 ----
    #pragma unroll
    for (int e = 0; e < 2; ++e) {
        const int idx = tid + e * 256;
        const int r = idx >> 5, cx = idx & 31;
        Alds[r * A_STR + cx] =
            f2bf(warm[(size_t)(row0 + r) * (T_WARM * F_WARM) + cx]);   // t=0
    }
    #pragma unroll
    for (int e = 0; e < 8; ++e) {
        const int idx = tid + e * 256;
        const int r = idx >> 7, c = idx & 127;
        Alds[r * A_STR + F_WARM + c] = f2bf(h0[(size_t)(row0 + r) * H_DIM + hb + c]);
    }
    // ---- phf init: partner h0 frags ----
    short8 phf[4];
    #pragma unroll
    for (int c = 0; c < 4; ++c) {
        short8 f;
        #pragma unroll
        for (int i = 0; i < 8; ++i)
            f[i] = f2bf(h0[(size_t)(row0 + n16) * H_DIM + qb + c * 32 + kg * 8 + i]);
        phf[c] = f;
    }

    const short* abase = &Alds[n16 * A_STR + kg * 8];   // x at +0, own-h c at +32+c*32
    const short8* wsW8 = (const short8*)wsWl;

    for (int t = 0; t < T_TOTAL; ++t) {
        __syncthreads();                                // A: Alds + phf(h_{t-1}) ready

        // ---- async prefetch x_{t+1} ----
        const int tn = t + 1;
        if (tn < T_TOTAL) {
            #pragma unroll
            for (int e = 0; e < 2; ++e) {
                const int idx = tid + e * 256;
                const int r = idx >> 5, cx = idx & 31;
                const float* gp;
                if (tn < T_WARM)
                    gp = &warm[(size_t)(row0 + r) * (T_WARM * F_WARM)
                               + (size_t)tn * F_WARM + cx];
                else
                    gp = &autoin[(size_t)(row0 + r) * (T_WARM * F_AUTO)
                                 + (size_t)(tn - T_WARM) * F_AUTO
                                 + ((cx < F_AUTO) ? cx : 0)];
                __builtin_amdgcn_global_load_lds(
                    (const GLOBAL_AS void*)gp,
                    (LDS_AS void*)&xstage[e * 256 + w * 64], 4, 0, 0);
            }
        }

        // ---- wave0: y_{t-1} from full h_{t-1} (own LDS + phf), both halves ----
        if (w == 0 && t >= 1) {
            float4v ya = (float4v){bout, bout, bout, bout};
            #pragma unroll
            for (int c = 0; c < 4; ++c)                 // own chunks, gc = hb/32+c
                ya = __builtin_amdgcn_mfma_f32_16x16x32_bf16(
                         *(const short8*)(abase + 32 + c * 32),
                         wsW8[(hb / 32 + c) * 64 + l], ya, 0, 0, 0);
            #pragma unroll
            for (int c = 0; c < 4; ++c)                 // partner chunks
                ya = __builtin_amdgcn_mfma_f32_16x16x32_bf16(
                         phf[c], wsW8[(qb / 32 + c) * 64 + l], ya, 0, 0, 0);
            if (n16 < O_DIM) {
                if (half == 0) {
                    #pragma unroll
                    for (int r = 0; r < 4; ++r)
                        out[(size_t)(row0 + kg * 4 + r) * (T_TOTAL * O_DIM)
                            + (size_t)(t - 1) * O_DIM + n16] = ya[r];
                }
                if (t >= T_WARM) {                      // feedback cols [24,32)
                    #pragma unroll
                    for (int r = 0; r < 4; ++r)
                        Alds[(kg * 4 + r) * A_STR + F_AUTO + n16] = f2bf(ya[r]);
                }
            }
        }

        // ---- K-loop: own 4 + partner 4 chunks, x chunk last ----
        float4v acc[4][2];
        #pragma unroll
        for (int g = 0; g < 4; ++g)
            #pragma unroll
            for (int j = 0; j < 2; ++j)
                acc[g][j] = (float4v){0.f, 0.f, 0.f, 0.f};

        #pragma unroll
        for (int c = 0; c < 4; ++c) {
            const short8 af = *(const short8*)(abase + 32 + c * 32);
            #pragma unroll
            for (int g = 0; g < 4; ++g)
                #pragma unroll
                for (int j = 0; j < 2; ++j)
                    acc[g][j] = __builtin_amdgcn_mfma_f32_16x16x32_bf16(
                                    af, bwo[c][g][j], acc[g][j], 0, 0, 0);
        }
        #pragma unroll
        for (int c = 0; c < 4; ++c) {
            #pragma unroll
            for (int g = 0; g < 4; ++g)
                #pragma unroll
                for (int j = 0; j < 2; ++j)
                    acc[g][j] = __builtin_amdgcn_mfma_f32_16x16x32_bf16(
                                    phf[c], bwp[c][g][j], acc[g][j], 0, 0, 0);
        }

        if (t >= T_WARM) __syncthreads();               // B: feedback cols ready

        {
            const short8 af = *(const short8*)(abase);  // x chunk
            #pragma unroll
            for (int g = 0; g < 4; ++g)
                #pragma unroll
                for (int j = 0; j < 2; ++j)
                    acc[g][j] = __builtin_amdgcn_mfma_f32_16x16x32_bf16(
                                    af, bwx[g][j], acc[g][j], 0, 0, 0);
        }

        // ---- gates + c/h update (8 h-vals/thread) ----
        uint32_t hp[4];
        #pragma unroll
        for (int j = 0; j < 2; ++j) {
            const int cl = w * 32 + j * 16 + n16;
            const float b0 = biasL[cl];
            const float b1 = biasL[128 + cl];
            const float b2 = biasL[256 + cl];
            const float b3 = biasL[384 + cl];
            uint32_t u0 = 0, u1 = 0;
            #pragma unroll
            for (int r = 0; r < 4; ++r) {
                const float ig = sigmoid_(acc[0][j][r] + b0);
                const float fg = sigmoid_(acc[1][j][r] + b1);
                const float gg = tanh_(acc[2][j][r] + b2);
                const float og = sigmoid_(acc[3][j][r] + b3);
                const float cc = fg * creg[j][r] + ig * gg;
                creg[j][r] = cc;
                const float hh = og * tanh_(cc);
                const uint32_t hbv = (uint32_t)(uint16_t)f2bf(hh);
                if (r == 0) u0 = hbv;       else if (r == 1) u0 |= hbv << 16;
                else if (r == 2) u1 = hbv;  else              u1 |= hbv << 16;
            }
            hp[j * 2 + 0] = u0;
            hp[j * 2 + 1] = u1;
        }

        // ---- publish h_t to exchange buffer (global; no Alds hazard) ----
        {
            unsigned short* ob = obuf0 + (t & 1) * 2048;
            #pragma unroll
            for (int j = 0; j < 2; ++j) {
                const int cl = w * 32 + j * 16 + n16;
                const uint32_t u0 = hp[j * 2], u1 = hp[j * 2 + 1];
                ob[(kg * 4 + 0) * 128 + cl] = (unsigned short)(u0 & 0xFFFF);
                ob[(kg * 4 + 1) * 128 + cl] = (unsigned short)(u0 >> 16);
                ob[(kg * 4 + 2) * 128 + cl] = (unsigned short)(u1 & 0xFFFF);
                ob[(kg * 4 + 3) * 128 + cl] = (unsigned short)(u1 >> 16);
            }
        }

        __syncthreads();                                // C: A reads done; vmcnt drained

        // ---- write own h_t into Alds ----
        #pragma unroll
        for (int j = 0; j < 2; ++j) {
            const int cl = F_WARM + w * 32 + j * 16 + n16;
            const uint32_t u0 = hp[j * 2], u1 = hp[j * 2 + 1];
            Alds[(kg * 4 + 0) * A_STR + cl] = (short)(u0 & 0xFFFF);
            Alds[(kg * 4 + 1) * A_STR + cl] = (short)(u0 >> 16);
            Alds[(kg * 4 + 2) * A_STR + cl] = (short)(u1 & 0xFFFF);
            Alds[(kg * 4 + 3) * A_STR + cl] = (short)(u1 >> 16);
        }
        // ---- commit prefetched x_{t+1} ----
        if (tn < T_TOTAL) {
            #pragma unroll
            for (int e = 0; e < 2; ++e) {
                const int idx = tid + e * 256;
                const int r = idx >> 5, cx = idx & 31;
                if (tn < T_WARM || cx < F_AUTO)
                    Alds[r * A_STR + cx] = f2bf(xstage[idx]);
            }
        }

        // ---- flag publish (leader) + per-wave acquire poll + phf load ----
        if (tid == 0) {
            __threadfence();
            __hip_atomic_store(myflag, (uint32_t)(t + 1),
                               __ATOMIC_RELEASE, __HIP_MEMORY_SCOPE_AGENT);
        }
        {
            const uint32_t want = (uint32_t)(t + 1);
            while (__hip_atomic_load(pflag, __ATOMIC_ACQUIRE,
                                     __HIP_MEMORY_SCOPE_AGENT) < want)
                __builtin_amdgcn_s_sleep(1);
            const unsigned short* pb = pbuf0 + (t & 1) * 2048;
            #pragma unroll
            for (int c = 0; c < 4; ++c)
                phf[c] = *(const short8*)&pb[n16 * 128 + c * 32 + kg * 8];
        }
        // loop-top barrier A publishes Alds(h_t, x_{t+1}); phf holds partner h_t
    }

    // ---- epilogue: y_{T-1} ----
    __syncthreads();
    if (w == 0) {
        float4v ya = (float4v){bout, bout, bout, bout};
        #pragma unroll
        for (int c = 0; c < 4; ++c)
            ya = __builtin_amdgcn_mfma_f32_16x16x32_bf16(
                     *(const short8*)(abase + 32 + c * 32),
                     wsW8[(hb / 32 + c) * 64 + l], ya, 0, 0, 0);
        #pragma unroll
        for (int c = 0; c < 4; ++c)
            ya = __builtin_amdgcn_mfma_f32_16x16x32_bf16(
                     phf[c], wsW8[(qb / 32 + c) * 64 + l], ya, 0, 0, 0);
        if (half == 0 && n16 < O_DIM) {
            #pragma unroll
            for (int r = 0; r < 4; ++r)
                out[(size_t)(row0 + kg * 4 + r) * (T_TOTAL * O_DIM)
                    + (size_t)(T_TOTAL - 1) * O_DIM + n16] = ya[r];
        }
    }
}

extern "C" void kernel_launch(void* const* d_in, const int* in_sizes, int n_in,
                              void* d_out, int out_size, void* d_ws, size_t ws_size,
                              hipStream_t stream) {
    (void)in_sizes; (void)n_in; (void)out_size; (void)ws_size;
    const float* c0   = (const float*)d_in[0];
    const float* h0   = (const float*)d_in[1];
    const float* warm = (const float*)d_in[2];
    const float* aut  = (const float*)d_in[3];
    const float* Wih  = (const float*)d_in[4];
    const float* Whh  = (const float*)d_in[5];
    const float* b    = (const float*)d_in[6];
    const float* Wout = (const float*)d_in[7];
    const float* bout = (const float*)d_in[8];
    float* out = (float*)d_out;
    unsigned short* ws = (unsigned short*)d_ws;
    // ws layout: [0,8KB) flags (64B/WG, zeroed each launch);
    //            [8KB, 8KB+1MB) h-exchange: per WG 2 x 4KB ping-pong.
    hipMemsetAsync(d_ws, 0, 8192, stream);
    hipLaunchKernelGGL(lstm_pair, dim3(128), dim3(256), 0, stream,
                       c0, h0, warm, aut, Wih, Whh, b, Wout, bout, out, ws);
}

// Round 3
// 7155.858 us; speedup vs baseline: 2.1746x; 2.1746x over previous
//
#include <hip/hip_runtime.h>
#include <stdint.h>

// R7: R6's 2-way N-split + cache-maintenance-free exchange (R6: 15561 us,
// R5: 7774 us). R6's failure: __threadfence + REL/ACQ agent atomics emit
// buffer_wbl2/buffer_inv -> full L2 flush+inv per step per WG (~21k cy/step,
// WRITE_SIZE 587 MB all slow-path). R7:
//  - exchange data/flags are RELAXED SYSTEM-scope atomics (sc0 sc1: bypass
//    L1/L2, L3-resident, ~700cy) -> zero cache-maintenance instructions.
//  - release = data stores drained by barrier C's vmcnt(0), then tid0 stores
//    flag (relaxed). acquire = relaxed flag poll; data loads are sc-bypass so
//    no inv needed. No __threadfence anywhere.
//  - publish end of step t, consume start of step t+1: poll expected-hit,
//    phf loads issued at step top, first used after own-half MFMAs (hidden).
//  - exchange layout: u32 row-pair words (rows 2rp,2rp+1 of col cl at
//    ex[cl*8+rp]) -> producer: 4 clean u32 stores; consumer: 32 u32 loads +
//    ~80 VALU extraction (hidden).
//  - y after own-chunk MFMAs (reuses afh frags + phf); feedback from ya regs
//    before barrier B. Barriers/step: 2 warm, 3 auto.

#define B_TOTAL   1024
#define H_DIM     256
#define F_WARM    32
#define F_AUTO    24
#define O_DIM     8
#define T_WARM    512
#define T_TOTAL   1024
#define N4H       1024
#define A_STR     168   // x(32)+h(128)+pad(8): 336 B/row, 16B-aligned, 2-way banks

typedef __attribute__((ext_vector_type(8))) short short8;
typedef __attribute__((ext_vector_type(4))) float float4v;

#define GLOBAL_AS __attribute__((address_space(1)))
#define LDS_AS    __attribute__((address_space(3)))

__device__ __forceinline__ short f2bf(float x) {
    union { float f; uint32_t u; } v; v.f = x;
    uint32_t r = v.u + 0x7FFFu + ((v.u >> 16) & 1u);   // RNE
    return (short)(r >> 16);
}
__device__ __forceinline__ float sigmoid_(float x) {
    const float e = __expf(-x);
    return __builtin_amdgcn_rcpf(1.0f + e);
}
__device__ __forceinline__ float tanh_(float x) {
    const float e = __expf(-2.0f * fabsf(x));
    const float t = (1.0f - e) * __builtin_amdgcn_rcpf(1.0f + e);
    return x >= 0.0f ? t : -t;
}

__global__ __launch_bounds__(256, 1)
void lstm_pair(const float* __restrict__ c0, const float* __restrict__ h0,
               const float* __restrict__ warm, const float* __restrict__ autoin,
               const float* __restrict__ W_ih, const float* __restrict__ W_hh,
               const float* __restrict__ bvec, const float* __restrict__ W_out,
               const float* __restrict__ b_out, float* __restrict__ out,
               unsigned short* __restrict__ ws)
{
    const int tid  = threadIdx.x;
    const int w    = tid >> 6;        // wave 0..3 -> own h-units [w*32, +32)
    const int l    = tid & 63;
    const int n16  = l & 15;          // MFMA n / A row (m)
    const int kg   = l >> 4;          // k-group 0..3
    const int bid  = blockIdx.x;
    const int half = bid >> 6;        // N-half: h-units [half*128, +128)
    const int row0 = (bid & 63) * 16; // batch rows
    const int hb   = half * 128;      // own h base (global h index)
    const int qb   = 128 - hb;        // partner h base

    uint32_t*       myflag = (uint32_t*)((char*)ws + (size_t)bid * 64);
    uint32_t*       pflag  = (uint32_t*)((char*)ws + (size_t)(bid ^ 64) * 64);
    uint32_t*       obuf32 = (uint32_t*)((char*)ws + 8192) + (size_t)bid * 2048;
    uint32_t*       pbuf32 = (uint32_t*)((char*)ws + 8192) + (size_t)(bid ^ 64) * 2048;

    __shared__ __align__(16) short Alds[16 * A_STR];    // [x(32) | own h(128) | pad]
    __shared__ __align__(16) unsigned short wsWl[4096]; // W_out MFMA B-frags
    __shared__ float biasL[512];                        // own 4 gates x 128
    __shared__ __align__(16) float xstage[512];         // x_{t+1} prefetch

    // ---- W_out frags -> LDS (kk=0..7 over K=256, cols 0..15, n>=8 zero) ----
    for (int idx = tid; idx < 4096; idx += 256) {
        const int i = idx & 7, lane = (idx >> 3) & 63, kk = idx >> 9;
        const int k = kk * 32 + (lane >> 4) * 8 + i;
        const int n = lane & 15;
        wsWl[idx] = (unsigned short)((n < O_DIM) ? f2bf(W_out[k * O_DIM + n]) : (short)0);
    }
    // ---- bias: own 512 cols, layout [g][128] ----
    #pragma unroll
    for (int e = 0; e < 2; ++e) {
        const int idx = tid + e * 256;
        const int g = idx >> 7, loc = idx & 127;
        biasL[idx] = bvec[g * 256 + hb + loc];
    }

    // ---- register weights: 72 frags = 288 VGPR (compile-time indexed) ----
    short8 bwx[4][2];       // x chunk (W_ih rows 0..31)
    short8 bwo[4][4][2];    // own-h chunks c=0..3
    short8 bwp[4][4][2];    // partner-h chunks
    #pragma unroll
    for (int g = 0; g < 4; ++g)
        #pragma unroll
        for (int j = 0; j < 2; ++j) {
            const int col = g * 256 + hb + w * 32 + j * 16 + n16;
            {
                short8 f;
                #pragma unroll
                for (int i = 0; i < 8; ++i)
                    f[i] = f2bf(W_ih[(kg * 8 + i) * N4H + col]);
                bwx[g][j] = f;
            }
            #pragma unroll
            for (int c = 0; c < 4; ++c) {
                short8 f, p;
                #pragma unroll
                for (int i = 0; i < 8; ++i) {
                    const int kr = c * 32 + kg * 8 + i;
                    f[i] = f2bf(W_hh[(hb + kr) * N4H + col]);
                    p[i] = f2bf(W_hh[(qb + kr) * N4H + col]);
                }
                bwo[c][g][j] = f;
                bwp[c][g][j] = p;
            }
        }

    const float bout = (w == 0 && n16 < O_DIM) ? b_out[n16] : 0.0f;

    // ---- c state ----
    float creg[2][4];
    #pragma unroll
    for (int j = 0; j < 2; ++j)
        #pragma unroll
        for (int r = 0; r < 4; ++r)
            creg[j][r] = c0[(size_t)(row0 + kg * 4 + r) * H_DIM
                            + (hb + w * 32 + j * 16 + n16)];

    // ---- initial A: x_0 + own h0 ----
    #pragma unroll
    for (int e = 0; e < 2; ++e) {
        const int idx = tid + e * 256;
        const int r = idx >> 5, cx = idx & 31;
        Alds[r * A_STR + cx] =
            f2bf(warm[(size_t)(row0 + r) * (T_WARM * F_WARM) + cx]);   // t=0
    }
    #pragma unroll
    for (int e = 0; e < 8; ++e) {
        const int idx = tid + e * 256;
        const int r = idx >> 7, c = idx & 127;
        Alds[r * A_STR + F_WARM + c] = f2bf(h0[(size_t)(row0 + r) * H_DIM + hb + c]);
    }
    // ---- phf init: partner h0 frags ----
    short8 phf[4];
    #pragma unroll
    for (int c = 0; c < 4; ++c) {
        short8 f;
        #pragma unroll
        for (int i = 0; i < 8; ++i)
            f[i] = f2bf(h0[(size_t)(row0 + n16) * H_DIM + qb + c * 32 + kg * 8 + i]);
        phf[c] = f;
    }

    const short* abase = &Alds[n16 * A_STR + kg * 8];
    const short8* wsW8 = (const short8*)wsWl;
    const int shx = (n16 & 1) * 16;                     // row half in u32 word

    for (int t = 0; t < T_TOTAL; ++t) {
        __syncthreads();                                // A: Alds(h_{t-1}, x_t) ready

        // ---- async prefetch x_{t+1} ----
        const int tn = t + 1;
        if (tn < T_TOTAL) {
            #pragma unroll
            for (int e = 0; e < 2; ++e) {
                const int idx = tid + e * 256;
                const int r = idx >> 5, cx = idx & 31;
                const float* gp;
                if (tn < T_WARM)
                    gp = &warm[(size_t)(row0 + r) * (T_WARM * F_WARM)
                               + (size_t)tn * F_WARM + cx];
                else
                    gp = &autoin[(size_t)(row0 + r) * (T_WARM * F_AUTO)
                                 + (size_t)(tn - T_WARM) * F_AUTO
                                 + ((cx < F_AUTO) ? cx : 0)];
                __builtin_amdgcn_global_load_lds(
                    (const GLOBAL_AS void*)gp,
                    (LDS_AS void*)&xstage[e * 256 + w * 64], 4, 0, 0);
            }
        }

        // ---- own A-frags (reused by K-loop and y) ----
        short8 afh[4];
        #pragma unroll
        for (int c = 0; c < 4; ++c)
            afh[c] = *(const short8*)(abase + 32 + c * 32);

        // ---- poll partner flag >= t, then issue phf loads (h_{t-1}) ----
        if (t >= 1) {
            while (__hip_atomic_load(pflag, __ATOMIC_RELAXED,
                                     __HIP_MEMORY_SCOPE_SYSTEM) < (uint32_t)t)
                __builtin_amdgcn_s_sleep(1);
            asm volatile("" ::: "memory");
            const uint32_t* pb = pbuf32 + ((t - 1) & 1) * 1024;
            #pragma unroll
            for (int c = 0; c < 4; ++c) {
                uint32_t wv[8];
                #pragma unroll
                for (int i = 0; i < 8; ++i)
                    wv[i] = __hip_atomic_load(&pb[(c * 32 + kg * 8 + i) * 8 + (n16 >> 1)],
                                              __ATOMIC_RELAXED, __HIP_MEMORY_SCOPE_SYSTEM);
                short8 f;
                #pragma unroll
                for (int i = 0; i < 8; ++i)
                    f[i] = (short)((wv[i] >> shx) & 0xFFFFu);
                phf[c] = f;
            }
        }

        // ---- K-loop: own 4 chunks first (phf not needed yet) ----
        float4v acc[4][2];
        #pragma unroll
        for (int g = 0; g < 4; ++g)
            #pragma unroll
            for (int j = 0; j < 2; ++j)
                acc[g][j] = (float4v){0.f, 0.f, 0.f, 0.f};

        #pragma unroll
        for (int c = 0; c < 4; ++c)
            #pragma unroll
            for (int g = 0; g < 4; ++g)
                #pragma unroll
                for (int j = 0; j < 2; ++j)
                    acc[g][j] = __builtin_amdgcn_mfma_f32_16x16x32_bf16(
                                    afh[c], bwo[c][g][j], acc[g][j], 0, 0, 0);

        // ---- partner 4 chunks ----
        #pragma unroll
        for (int c = 0; c < 4; ++c)
            #pragma unroll
            for (int g = 0; g < 4; ++g)
                #pragma unroll
                for (int j = 0; j < 2; ++j)
                    acc[g][j] = __builtin_amdgcn_mfma_f32_16x16x32_bf16(
                                    phf[c], bwp[c][g][j], acc[g][j], 0, 0, 0);

        // ---- wave0: y_{t-1} from afh (own h_{t-1}) + phf (partner) ----
        if (w == 0 && t >= 1) {
            float4v ya = (float4v){bout, bout, bout, bout};
            #pragma unroll
            for (int c = 0; c < 4; ++c)
                ya = __builtin_amdgcn_mfma_f32_16x16x32_bf16(
                         afh[c], wsW8[(hb / 32 + c) * 64 + l], ya, 0, 0, 0);
            #pragma unroll
            for (int c = 0; c < 4; ++c)
                ya = __builtin_amdgcn_mfma_f32_16x16x32_bf16(
                         phf[c], wsW8[(qb / 32 + c) * 64 + l], ya, 0, 0, 0);
            if (n16 < O_DIM) {
                if (half == 0) {
                    #pragma unroll
                    for (int r = 0; r < 4; ++r)
                        out[(size_t)(row0 + kg * 4 + r) * (T_TOTAL * O_DIM)
                            + (size_t)(t - 1) * O_DIM + n16] = ya[r];
                }
                if (t >= T_WARM) {                      // feedback cols [24,32)
                    #pragma unroll
                    for (int r = 0; r < 4; ++r)
                        Alds[(kg * 4 + r) * A_STR + F_AUTO + n16] = f2bf(ya[r]);
                }
            }
        }

        if (t >= T_WARM) __syncthreads();               // B: feedback cols ready

        {
            const short8 af = *(const short8*)(abase);  // x chunk (+feedback)
            #pragma unroll
            for (int g = 0; g < 4; ++g)
                #pragma unroll
                for (int j = 0; j < 2; ++j)
                    acc[g][j] = __builtin_amdgcn_mfma_f32_16x16x32_bf16(
                                    af, bwx[g][j], acc[g][j], 0, 0, 0);
        }

        // ---- gates + c/h update (8 h-vals/thread) ----
        uint32_t hp[4];
        #pragma unroll
        for (int j = 0; j < 2; ++j) {
            const int cl = w * 32 + j * 16 + n16;
            const float b0 = biasL[cl];
            const float b1 = biasL[128 + cl];
            const float b2 = biasL[256 + cl];
            const float b3 = biasL[384 + cl];
            uint32_t u0 = 0, u1 = 0;
            #pragma unroll
            for (int r = 0; r < 4; ++r) {
                const float ig = sigmoid_(acc[0][j][r] + b0);
                const float fg = sigmoid_(acc[1][j][r] + b1);
                const float gg = tanh_(acc[2][j][r] + b2);
                const float og = sigmoid_(acc[3][j][r] + b3);
                const float cc = fg * creg[j][r] + ig * gg;
                creg[j][r] = cc;
                const float hh = og * tanh_(cc);
                const uint32_t hbv = (uint32_t)(uint16_t)f2bf(hh);
                if (r == 0) u0 = hbv;       else if (r == 1) u0 |= hbv << 16;
                else if (r == 2) u1 = hbv;  else              u1 |= hbv << 16;
            }
            hp[j * 2 + 0] = u0;
            hp[j * 2 + 1] = u1;
        }

        // ---- publish h_t: u32 row-pair words, relaxed system-scope ----
        {
            uint32_t* ob = obuf32 + (t & 1) * 1024;
            #pragma unroll
            for (int j = 0; j < 2; ++j) {
                const int cl = w * 32 + j * 16 + n16;
                #pragma unroll
                for (int p = 0; p < 2; ++p)
                    __hip_atomic_store(&ob[cl * 8 + kg * 2 + p], hp[j * 2 + p],
                                       __ATOMIC_RELAXED, __HIP_MEMORY_SCOPE_SYSTEM);
            }
        }

        __syncthreads();                        // C: vmcnt(0) drains publishes

        if (tid == 0)                           // release: after-barrier flag
            __hip_atomic_store(myflag, (uint32_t)(t + 1),
                               __ATOMIC_RELAXED, __HIP_MEMORY_SCOPE_SYSTEM);

        // ---- write own h_t into Alds ----
        #pragma unroll
        for (int j = 0; j < 2; ++j) {
            const int cl = F_WARM + w * 32 + j * 16 + n16;
            const uint32_t u0 = hp[j * 2], u1 = hp[j * 2 + 1];
            Alds[(kg * 4 + 0) * A_STR + cl] = (short)(u0 & 0xFFFF);
            Alds[(kg * 4 + 1) * A_STR + cl] = (short)(u0 >> 16);
            Alds[(kg * 4 + 2) * A_STR + cl] = (short)(u1 & 0xFFFF);
            Alds[(kg * 4 + 3) * A_STR + cl] = (short)(u1 >> 16);
        }
        // ---- commit prefetched x_{t+1} ----
        if (tn < T_TOTAL) {
            #pragma unroll
            for (int e = 0; e < 2; ++e) {
                const int idx = tid + e * 256;
                const int r = idx >> 5, cx = idx & 31;
                if (tn < T_WARM || cx < F_AUTO)
                    Alds[r * A_STR + cx] = f2bf(xstage[idx]);
            }
        }
        // loop-top barrier A publishes Alds(h_t, x_{t+1})
    }

    // ---- epilogue: y_{T-1} (needs partner h_{T-1}) ----
    __syncthreads();
    {
        while (__hip_atomic_load(pflag, __ATOMIC_RELAXED,
                                 __HIP_MEMORY_SCOPE_SYSTEM) < (uint32_t)T_TOTAL)
            __builtin_amdgcn_s_sleep(1);
        asm volatile("" ::: "memory");
        const uint32_t* pb = pbuf32 + ((T_TOTAL - 1) & 1) * 1024;
        #pragma unroll
        for (int c = 0; c < 4; ++c) {
            uint32_t wv[8];
            #pragma unroll
            for (int i = 0; i < 8; ++i)
                wv[i] = __hip_atomic_load(&pb[(c * 32 + kg * 8 + i) * 8 + (n16 >> 1)],
                                          __ATOMIC_RELAXED, __HIP_MEMORY_SCOPE_SYSTEM);
            short8 f;
            #pragma unroll
            for (int i = 0; i < 8; ++i)
                f[i] = (short)((wv[i] >> shx) & 0xFFFFu);
            phf[c] = f;
        }
    }
    if (w == 0) {
        float4v ya = (float4v){bout, bout, bout, bout};
        #pragma unroll
        for (int c = 0; c < 4; ++c)
            ya = __builtin_amdgcn_mfma_f32_16x16x32_bf16(
                     *(const short8*)(abase + 32 + c * 32),
                     wsW8[(hb / 32 + c) * 64 + l], ya, 0, 0, 0);
        #pragma unroll
        for (int c = 0; c < 4; ++c)
            ya = __builtin_amdgcn_mfma_f32_16x16x32_bf16(
                     phf[c], wsW8[(qb / 32 + c) * 64 + l], ya, 0, 0, 0);
        if (half == 0 && n16 < O_DIM) {
            #pragma unroll
            for (int r = 0; r < 4; ++r)
                out[(size_t)(row0 + kg * 4 + r) * (T_TOTAL * O_DIM)
                    + (size_t)(T_TOTAL - 1) * O_DIM + n16] = ya[r];
        }
    }
}

extern "C" void kernel_launch(void* const* d_in, const int* in_sizes, int n_in,
                              void* d_out, int out_size, void* d_ws, size_t ws_size,
                              hipStream_t stream) {
    (void)in_sizes; (void)n_in; (void)out_size; (void)ws_size;
    const float* c0   = (const float*)d_in[0];
    const float* h0   = (const float*)d_in[1];
    const float* warm = (const float*)d_in[2];
    const float* aut  = (const float*)d_in[3];
    const float* Wih  = (const float*)d_in[4];
    const float* Whh  = (const float*)d_in[5];
    const float* b    = (const float*)d_in[6];
    const float* Wout = (const float*)d_in[7];
    const float* bout = (const float*)d_in[8];
    float* out = (float*)d_out;
    unsigned short* ws = (unsigned short*)d_ws;
    // ws layout: [0,8KB) flags (64B/WG, zeroed each launch);
    //            [8KB, 8KB+1MB) h-exchange: per WG 2 x 4KB u32 ping-pong.
    hipMemsetAsync(d_ws, 0, 8192, stream);
    hipLaunchKernelGGL(lstm_pair, dim3(128), dim3(256), 0, stream,
                       c0, h0, warm, aut, Wih, Whh, b, Wout, bout, out, ws);
}